// Round 8
// baseline (558.139 us; speedup 1.0000x reference)
//
#include <hip/hip_runtime.h>
#include <hip/hip_fp16.h>

// ---------------------------------------------------------------------------
// GCNModelWPathways: 3-layer GCN (N nodes, BS=8 batch, H=64) + committee
// pathway pooling + 2-layer MLP head + log_softmax.
//
// Layout strategy (R5): node features stored [b][n][h], b = blockIdx % 8 in
// linear+agg so each XCD owns one batch slice (L2 locality heuristic).
//
// R7: fp16 node features. fp32 slice (3.87MB) + csr (1.2MB) + hout write
// allocation > 4MB XCD L2 -> thrash (agg FETCH was 43MB vs 0 ideal).
// Half features: slice 1.94MB -> resident. Accumulation stays fp32.
// Plus: nt stores for hout / nt loads for csr (don't evict ms), and
// csr-index software pipelining (prefetch next 4 while gathering 4).
//
// R6 kept: dinv pre-scaling folded into linear (ms = dinv ⊙ hW^T); agg lane
// remap eg=lane>>4 (edge slot), hq=lane&15 (h quad) -> 4 edges in flight.
// R4 kept: __launch_bounds__(256,1) on linear (else 64-VGPR tier spills).
// ---------------------------------------------------------------------------

using uint2v = __attribute__((ext_vector_type(2))) unsigned int;

__global__ void count_kernel(const int* __restrict__ dst, int* __restrict__ degi, int E) {
  int e = blockIdx.x * blockDim.x + threadIdx.x;
  if (e < E) atomicAdd(&degi[dst[e]], 1);
}

// single-block exclusive prefix sum over counts[0..n) -> row_start[0..n]
__global__ void prefix_kernel(const int* __restrict__ counts, int* __restrict__ row_start, int n) {
  __shared__ int sums[1024];
  int t = threadIdx.x;
  int chunk = (n + 1023) >> 10;
  int beg = t * chunk;
  int end = min(beg + chunk, n);
  int s = 0;
  for (int i = beg; i < end; ++i) s += counts[i];
  sums[t] = s;
  __syncthreads();
  for (int d = 1; d < 1024; d <<= 1) {
    int v = (t >= d) ? sums[t - d] : 0;
    __syncthreads();
    sums[t] += v;
    __syncthreads();
  }
  int off = (t == 0) ? 0 : sums[t - 1];
  for (int i = beg; i < end; ++i) { row_start[i] = off; off += counts[i]; }
  if (end == n) row_start[n] = off;  // all such threads write the total
}

__global__ void fill_kernel(const int* __restrict__ src, const int* __restrict__ dst,
                            const int* __restrict__ row_start, int* __restrict__ cursor,
                            int* __restrict__ csr, int E) {
  int e = blockIdx.x * blockDim.x + threadIdx.x;
  if (e < E) {
    int d = dst[e];
    int pos = atomicAdd(&cursor[d], 1);
    csr[row_start[d] + pos] = src[e];
  }
}

__global__ void dinv_kernel(const int* __restrict__ degi, float* __restrict__ dinv, int N) {
  int n = blockIdx.x * blockDim.x + threadIdx.x;
  if (n < N) dinv[n] = rsqrtf((float)(degi[n] + 1));  // +1: self-loop
}

// Register-tiled linear on one b-slice:
//   ms[b][r][h] = (half) dinv[r] * sum_f H[b][r][f] * W[h][f]
// Grid = ceil(N/64)*BS; b = blockIdx % BS (XCD-aligned); 256 threads;
// 64 rows x 64 h per block; 4x4 tile per thread in named float4 registers.
// IN_HALF: input features are fp16 (layers 2,3); else fp32 (layer 1: x).
template <bool IN_HALF>
__global__ __launch_bounds__(256, 1)  // release VGPR budget; no 64-reg tier spills
void linear_kernel(const void* __restrict__ hin, const float* __restrict__ W,
                   const float* __restrict__ dinv, __half* __restrict__ ms,
                   int N, int BS) {
  __shared__ __align__(16) float Xs[64][68];
  __shared__ __align__(16) float Wt[64][68];  // Wt[f][h]
  int t = threadIdx.x;
  int b = blockIdx.x % BS;
  int chunk = blockIdx.x / BS;
  int row0 = chunk * 64;                 // node index within slice
  int nrows = min(64, N - row0);
  size_t sbase = ((size_t)b * N + row0) * 64;

  // stage W transposed (coalesced read, scattered LDS write; once per block)
  for (int i = t; i < 4096; i += 256) {
    int h = i >> 6, f = i & 63;
    Wt[f][h] = W[i];
  }
  // stage X tile: 4 threads per row
  {
    int rr = t >> 2;   // 0..63
    int c0 = t & 3;
    bool valid = rr < nrows;
    if (IN_HALF) {
      // row = 64 halves; thread covers halves [c0*16, c0*16+16)
      float* dst = &Xs[rr][c0 * 16];
      if (valid) {
        const __half* srcp = (const __half*)hin + sbase + (size_t)rr * 64 + c0 * 16;
        uint4 ra = *reinterpret_cast<const uint4*>(srcp);
        uint4 rb = *reinterpret_cast<const uint4*>(srcp + 8);
        float2 f;
        f = __half22float2(__builtin_bit_cast(__half2, ra.x)); dst[0] = f.x; dst[1] = f.y;
        f = __half22float2(__builtin_bit_cast(__half2, ra.y)); dst[2] = f.x; dst[3] = f.y;
        f = __half22float2(__builtin_bit_cast(__half2, ra.z)); dst[4] = f.x; dst[5] = f.y;
        f = __half22float2(__builtin_bit_cast(__half2, ra.w)); dst[6] = f.x; dst[7] = f.y;
        f = __half22float2(__builtin_bit_cast(__half2, rb.x)); dst[8] = f.x; dst[9] = f.y;
        f = __half22float2(__builtin_bit_cast(__half2, rb.y)); dst[10] = f.x; dst[11] = f.y;
        f = __half22float2(__builtin_bit_cast(__half2, rb.z)); dst[12] = f.x; dst[13] = f.y;
        f = __half22float2(__builtin_bit_cast(__half2, rb.w)); dst[14] = f.x; dst[15] = f.y;
      } else {
#pragma unroll
        for (int k = 0; k < 16; ++k) dst[k] = 0.f;
      }
    } else {
      const float* srcp = (const float*)hin + sbase + (size_t)rr * 64;
#pragma unroll
      for (int c = 0; c < 4; ++c) {
        int f4 = c0 + c * 4;
        float4 v = valid ? reinterpret_cast<const float4*>(srcp)[f4]
                         : float4{0.f, 0.f, 0.f, 0.f};
        *reinterpret_cast<float4*>(&Xs[rr][4 * f4]) = v;
      }
    }
  }
  __syncthreads();

  int hg = t & 15;   // h0 = 4*hg
  int rg = t >> 4;   // r0 = 4*rg
  int r0 = 4 * rg;

  float4 acc0 = {0.f, 0.f, 0.f, 0.f};
  float4 acc1 = {0.f, 0.f, 0.f, 0.f};
  float4 acc2 = {0.f, 0.f, 0.f, 0.f};
  float4 acc3 = {0.f, 0.f, 0.f, 0.f};

// NOTE: macro params must NOT be named x/y/z/w (round-3 compile failure).
#define FMA4(A, S, V)            \
  A.x = fmaf((S), (V).x, A.x);   \
  A.y = fmaf((S), (V).y, A.y);   \
  A.z = fmaf((S), (V).z, A.z);   \
  A.w = fmaf((S), (V).w, A.w);

#pragma unroll
  for (int i = 0; i < 16; ++i) {  // f0 = 4*i
    float4 xr0 = *reinterpret_cast<const float4*>(&Xs[r0 + 0][4 * i]);
    float4 xr1 = *reinterpret_cast<const float4*>(&Xs[r0 + 1][4 * i]);
    float4 xr2 = *reinterpret_cast<const float4*>(&Xs[r0 + 2][4 * i]);
    float4 xr3 = *reinterpret_cast<const float4*>(&Xs[r0 + 3][4 * i]);
    float4 wv0 = *reinterpret_cast<const float4*>(&Wt[4 * i + 0][4 * hg]);
    float4 wv1 = *reinterpret_cast<const float4*>(&Wt[4 * i + 1][4 * hg]);
    float4 wv2 = *reinterpret_cast<const float4*>(&Wt[4 * i + 2][4 * hg]);
    float4 wv3 = *reinterpret_cast<const float4*>(&Wt[4 * i + 3][4 * hg]);
    FMA4(acc0, xr0.x, wv0); FMA4(acc0, xr0.y, wv1); FMA4(acc0, xr0.z, wv2); FMA4(acc0, xr0.w, wv3);
    FMA4(acc1, xr1.x, wv0); FMA4(acc1, xr1.y, wv1); FMA4(acc1, xr1.z, wv2); FMA4(acc1, xr1.w, wv3);
    FMA4(acc2, xr2.x, wv0); FMA4(acc2, xr2.y, wv1); FMA4(acc2, xr2.z, wv2); FMA4(acc2, xr2.w, wv3);
    FMA4(acc3, xr3.x, wv0); FMA4(acc3, xr3.y, wv1); FMA4(acc3, xr3.z, wv2); FMA4(acc3, xr3.w, wv3);
  }
#undef FMA4

  // epilogue: scale by dinv[row], convert to half, 8B store per thread
#define STORE_H(A, RIDX)                                                        \
  if ((RIDX) < nrows) {                                                         \
    float d = dinv[row0 + (RIDX)];                                              \
    __half2 p0 = __floats2half2_rn(A.x * d, A.y * d);                           \
    __half2 p1 = __floats2half2_rn(A.z * d, A.w * d);                           \
    uint2v st;                                                                  \
    st.x = __builtin_bit_cast(unsigned int, p0);                                \
    st.y = __builtin_bit_cast(unsigned int, p1);                                \
    *reinterpret_cast<uint2v*>(&ms[sbase + (size_t)(RIDX) * 64 + 4 * hg]) = st; \
  }
  STORE_H(acc0, r0 + 0)
  STORE_H(acc1, r0 + 1)
  STORE_H(acc2, r0 + 2)
  STORE_H(acc3, r0 + 3)
#undef STORE_H
}

// Pull aggregation on one b-slice. Grid = ceil(N/8)*BS; b = blockIdx % BS.
// Block = 512 threads = 8 waves; wave = one node. Lane remap: eg = lane>>4
// (edge slot 0..3), hq = lane&15 (h quad). Per step: 4 edges x 128B half rows
// gathered from the L2-resident ms slice; csr indices prefetched one step
// ahead (csr padded by 4 zeroed ints so tail prefetch is safe). fp32 accum.
template <bool WRITE_H>
__global__ void agg_kernel(const __half* __restrict__ ms, const float* __restrict__ dinv,
                           const float* __restrict__ bias, const int* __restrict__ row_start,
                           const int* __restrict__ csr, __half* __restrict__ hout,
                           float* __restrict__ q, const float* __restrict__ fcw,
                           int layer, int L, int N, int BS) {
  int b = blockIdx.x % BS;
  int chunk = blockIdx.x / BS;
  int w = threadIdx.x >> 6, lane = threadIdx.x & 63;
  int n = chunk * 8 + w;
  if (n >= N) return;
  int eg = lane >> 4;     // edge slot
  int hq = lane & 15;     // h quad: h = 4*hq .. 4*hq+3
  size_t bN = (size_t)b * N;
  const __half* mb = ms + bN * 64;

  float4 acc = {0.f, 0.f, 0.f, 0.f};
  // self-loop (counted once — eg 0 only)
  if (eg == 0) {
    uint2v r = *reinterpret_cast<const uint2v*>(mb + (size_t)n * 64 + 4 * hq);
    float2 f01 = __half22float2(__builtin_bit_cast(__half2, r.x));
    float2 f23 = __half22float2(__builtin_bit_cast(__half2, r.y));
    acc.x = f01.x; acc.y = f01.y; acc.z = f23.x; acc.w = f23.y;
  }

  int beg = row_start[n], end = row_start[n + 1];
  int deg = end - beg;
  int i = beg;
  int main_end = beg + (deg & ~3);
  if (i < main_end) {
    int s_cur = __builtin_nontemporal_load(csr + i + eg);
    while (true) {
      int inx = i + 4;
      // prefetch next step's index; tail reads the zeroed csr pad (safe, unused)
      int s_next = __builtin_nontemporal_load(csr + inx + eg);
      uint2v r = *reinterpret_cast<const uint2v*>(mb + (size_t)s_cur * 64 + 4 * hq);
      float2 f01 = __half22float2(__builtin_bit_cast(__half2, r.x));
      float2 f23 = __half22float2(__builtin_bit_cast(__half2, r.y));
      acc.x += f01.x; acc.y += f01.y; acc.z += f23.x; acc.w += f23.y;
      i = inx;
      if (i >= main_end) break;
      s_cur = s_next;
    }
  }
  int rem = end - i;  // 0..3
  if (rem > 0) {
    int e = i + ((eg < rem) ? eg : 0);
    int s = csr[e];
    uint2v r = *reinterpret_cast<const uint2v*>(mb + (size_t)s * 64 + 4 * hq);
    float2 f01 = __half22float2(__builtin_bit_cast(__half2, r.x));
    float2 f23 = __half22float2(__builtin_bit_cast(__half2, r.y));
    if (eg < rem) { acc.x += f01.x; acc.y += f01.y; acc.z += f23.x; acc.w += f23.y; }
  }

  // reduce across the 4 edge-slot groups (lanes differing in bits 4,5)
  acc.x += __shfl_xor(acc.x, 16); acc.y += __shfl_xor(acc.y, 16);
  acc.z += __shfl_xor(acc.z, 16); acc.w += __shfl_xor(acc.w, 16);
  acc.x += __shfl_xor(acc.x, 32); acc.y += __shfl_xor(acc.y, 32);
  acc.z += __shfl_xor(acc.z, 32); acc.w += __shfl_xor(acc.w, 32);

  float dn = dinv[n];
  float4 bias4 = *reinterpret_cast<const float4*>(&bias[4 * hq]);
  float4 val;
  val.x = fmaxf(fmaf(dn, acc.x, bias4.x), 0.f);
  val.y = fmaxf(fmaf(dn, acc.y, bias4.y), 0.f);
  val.z = fmaxf(fmaf(dn, acc.z, bias4.z), 0.f);
  val.w = fmaxf(fmaf(dn, acc.w, bias4.w), 0.f);

  if (WRITE_H && eg == 0) {
    __half2 p0 = __floats2half2_rn(val.x, val.y);
    __half2 p1 = __floats2half2_rn(val.z, val.w);
    uint2v st;
    st.x = __builtin_bit_cast(unsigned int, p0);
    st.y = __builtin_bit_cast(unsigned int, p1);
    // nt store: don't evict the ms slice from L2 (next linear streams this)
    __builtin_nontemporal_store(st, reinterpret_cast<uint2v*>(hout + bN * 64 + (size_t)n * 64 + 4 * hq));
  }

  // fc_w projection: q[n,b] (+)= sum_h val[h]*fcw[h*L+layer]
  int h0 = 4 * hq;
  float qp = val.x * fcw[(h0 + 0) * L + layer]
           + val.y * fcw[(h0 + 1) * L + layer]
           + val.z * fcw[(h0 + 2) * L + layer]
           + val.w * fcw[(h0 + 3) * L + layer];
  qp += __shfl_xor(qp, 1); qp += __shfl_xor(qp, 2);
  qp += __shfl_xor(qp, 4); qp += __shfl_xor(qp, 8);
  if (lane == 0) {
    if (layer == 0) q[bN + n] = qp;
    else q[bN + n] += qp;
  }
}

__global__ void pathway_kernel(const int* __restrict__ row, const int* __restrict__ col,
                               const float* __restrict__ q, float* __restrict__ s_sum,
                               float* __restrict__ cntc, int R, int N, int BS) {
  int idx = blockIdx.x * blockDim.x + threadIdx.x;
  if (idx >= R * BS) return;
  int r = idx / BS, b = idx - (idx / BS) * BS;
  int c = col[r], nd = row[r];
  atomicAdd(&s_sum[c * BS + b], q[(size_t)b * N + nd]);
  if (b == 0) atomicAdd(&cntc[c], 1.0f);
}

__global__ void head_kernel(const float* __restrict__ s_sum, const float* __restrict__ cntc,
                            const float* __restrict__ fcb, const float* __restrict__ l1w,
                            const float* __restrict__ l1b, const float* __restrict__ l2w,
                            const float* __restrict__ l2b, float* __restrict__ out,
                            int NCMT, int HFC, int NCLS, int BS) {
  int b = blockIdx.x;
  __shared__ float sbuf[400];
  __shared__ float z1[200];
  __shared__ float z2[8];
  int t = threadIdx.x;  // 256
  for (int c = t; c < NCMT; c += 256) {
    float cn = fmaxf(cntc[c], 1.0f);
    sbuf[c] = s_sum[c * BS + b] / cn + fcb[0];
  }
  __syncthreads();
  for (int j = t; j < HFC; j += 256) {
    float a = l1b[j];
    for (int c = 0; c < NCMT; ++c) a = fmaf(sbuf[c], l1w[j * NCMT + c], a);
    z1[j] = fmaxf(a, 0.f);
  }
  __syncthreads();
  if (t < NCLS) {
    float a = l2b[t];
    for (int j = 0; j < HFC; ++j) a = fmaf(z1[j], l2w[t * HFC + j], a);
    z2[t] = a;
  }
  __syncthreads();
  if (t == 0) {
    float mx = z2[0];
    for (int k = 1; k < NCLS; ++k) mx = fmaxf(mx, z2[k]);
    float se = 0.f;
    for (int k = 0; k < NCLS; ++k) se += expf(z2[k] - mx);
    float lse = mx + logf(se);
    for (int k = 0; k < NCLS; ++k) out[b * NCLS + k] = z2[k] - lse;
  }
}

extern "C" void kernel_launch(void* const* d_in, const int* in_sizes, int n_in,
                              void* d_out, int out_size, void* d_ws, size_t ws_size,
                              hipStream_t stream) {
  const float* x   = (const float*)d_in[0];
  const int*  ei   = (const int*)d_in[2];
  const int*  row  = (const int*)d_in[3];
  const int*  col  = (const int*)d_in[4];
  const float* W1  = (const float*)d_in[5];
  const float* b1  = (const float*)d_in[6];
  const float* W2  = (const float*)d_in[7];
  const float* b2  = (const float*)d_in[8];
  const float* W3  = (const float*)d_in[9];
  const float* b3  = (const float*)d_in[10];
  const float* fcw = (const float*)d_in[11];
  const float* fcb = (const float*)d_in[12];
  const float* l1w = (const float*)d_in[13];
  const float* l1b = (const float*)d_in[14];
  const float* l2w = (const float*)d_in[15];
  const float* l2b = (const float*)d_in[16];

  const int BS   = in_sizes[1];               // 8
  const int H    = in_sizes[6];               // 64
  const int F    = in_sizes[5] / H;           // 64
  const int N    = in_sizes[0] / (BS * F);    // 15135
  const int E    = in_sizes[2] / 2;           // 300000
  const int R    = in_sizes[3];               // 40000
  const int HFC  = in_sizes[14];              // 200
  const int NCMT = in_sizes[13] / HFC;        // 400
  const int NCLS = in_sizes[16];              // 2
  const int L    = in_sizes[11] / H;          // 3

  // workspace carve-out (256B aligned)
  char* p = (char*)d_ws;
  auto alloc = [&](size_t bytes) {
    void* r = (void*)p;
    p += (bytes + 255) & ~(size_t)255;
    return r;
  };
  int*   degi      = (int*)alloc((size_t)N * 4);
  int*   cursor    = (int*)alloc((size_t)N * 4);
  int*   row_start = (int*)alloc((size_t)(N + 1) * 4);
  int*   csr       = (int*)alloc((size_t)(E + 4) * 4);  // +4 pad for prefetch
  float* dinv      = (float*)alloc((size_t)N * 4);
  float* q         = (float*)alloc((size_t)N * BS * 4);
  float* s_sum     = (float*)alloc((size_t)NCMT * BS * 4);
  float* cntc      = (float*)alloc((size_t)NCMT * 4);
  __half* m        = (__half*)alloc((size_t)N * BS * H * 2);
  __half* hA       = (__half*)alloc((size_t)N * BS * H * 2);
  __half* hB       = (__half*)alloc((size_t)N * BS * H * 2);

  hipMemsetAsync(degi, 0, (size_t)N * 4, stream);
  hipMemsetAsync(cursor, 0, (size_t)N * 4, stream);
  hipMemsetAsync(csr + E, 0, 16, stream);  // zero the prefetch pad
  hipMemsetAsync(s_sum, 0, (size_t)NCMT * BS * 4, stream);
  hipMemsetAsync(cntc, 0, (size_t)NCMT * 4, stream);

  const int* e_src = ei;
  const int* e_dst = ei + E;

  count_kernel<<<(E + 255) / 256, 256, 0, stream>>>(e_dst, degi, E);
  prefix_kernel<<<1, 1024, 0, stream>>>(degi, row_start, N);
  fill_kernel<<<(E + 255) / 256, 256, 0, stream>>>(e_src, e_dst, row_start, cursor, csr, E);
  dinv_kernel<<<(N + 255) / 256, 256, 0, stream>>>(degi, dinv, N);

  int lin_grid = ((N + 63) / 64) * BS;   // b = blockIdx % BS -> XCD-pinned slices
  int agg_grid = ((N + 7) / 8) * BS;
  int agg_threads = 512;                 // 8 waves = 8 nodes per block

  // layer 1 (x is fp32 [b][n][f])
  linear_kernel<false><<<lin_grid, 256, 0, stream>>>(x, W1, dinv, m, N, BS);
  agg_kernel<true><<<agg_grid, agg_threads, 0, stream>>>(m, dinv, b1, row_start, csr, hA, q, fcw, 0, L, N, BS);
  // layer 2
  linear_kernel<true><<<lin_grid, 256, 0, stream>>>(hA, W2, dinv, m, N, BS);
  agg_kernel<true><<<agg_grid, agg_threads, 0, stream>>>(m, dinv, b2, row_start, csr, hB, q, fcw, 1, L, N, BS);
  // layer 3 — hout is dead (only q survives), skip the store
  linear_kernel<true><<<lin_grid, 256, 0, stream>>>(hB, W3, dinv, m, N, BS);
  agg_kernel<false><<<agg_grid, agg_threads, 0, stream>>>(m, dinv, b3, row_start, csr, nullptr, q, fcw, 2, L, N, BS);

  pathway_kernel<<<((size_t)R * BS + 255) / 256, 256, 0, stream>>>(row, col, q, s_sum, cntc, R, N, BS);
  head_kernel<<<BS, 256, 0, stream>>>(s_sum, cntc, fcb, l1w, l1b, l2w, l2b,
                                      (float*)d_out, NCMT, HFC, NCLS, BS);
}

// Round 11
// 535.914 us; speedup vs baseline: 1.0415x; 1.0415x over previous
//
#include <hip/hip_runtime.h>

// ---------------------------------------------------------------------------
// GCNModelWPathways: 3-layer GCN (N nodes, BS=8 batch, H=64) + committee
// pathway pooling + 2-layer MLP head + log_softmax.
//
// Layout (R5): node features [b][n][h] fp32; b = blockIdx % 8 in linear+agg
// so each XCD owns one 3.87MB batch slice (L2-resident gather heuristic).
// R10 lesson: fp16 features FAIL accuracy (absmax 1.56e-2 vs 1.41e-2 —
// 2 output-bf16 ulps; fp32 gives ~0). fp16 also bought zero time (agg is
// chain-latency-bound, not BW-bound). -> fp32 features, exact.
// R8 lesson: nt on csr loads forces ~900cy HBM reads on the DEPENDENT
// address chain -> csr must L2-cache. R10: csr stored as uint16 (N<65536),
// halving its footprint (0.6MB) and L2 pressure.
// R6/R7 kept: dinv pre-scaling in linear epilogue (ms = dinv ⊙ hW^T);
// agg lane remap eg=lane>>4 (edge slot), hq=lane&15 (h quad) -> one wave
// instruction gathers 4 edges x 256B; 1-step index prefetch; nt hout store.
// R4 kept: __launch_bounds__(256,1) on linear (else 64-VGPR tier spills).
// R9 lesson: nontemporal builtins need ext_vector_type, not HIP float4/uint4.
// ---------------------------------------------------------------------------

using f4v = __attribute__((ext_vector_type(4))) float;

__global__ void count_kernel(const int* __restrict__ dst, int* __restrict__ degi, int E) {
  int e = blockIdx.x * blockDim.x + threadIdx.x;
  if (e < E) atomicAdd(&degi[dst[e]], 1);
}

// single-block exclusive prefix sum over counts[0..n) -> row_start[0..n]
__global__ void prefix_kernel(const int* __restrict__ counts, int* __restrict__ row_start, int n) {
  __shared__ int sums[1024];
  int t = threadIdx.x;
  int chunk = (n + 1023) >> 10;
  int beg = t * chunk;
  int end = min(beg + chunk, n);
  int s = 0;
  for (int i = beg; i < end; ++i) s += counts[i];
  sums[t] = s;
  __syncthreads();
  for (int d = 1; d < 1024; d <<= 1) {
    int v = (t >= d) ? sums[t - d] : 0;
    __syncthreads();
    sums[t] += v;
    __syncthreads();
  }
  int off = (t == 0) ? 0 : sums[t - 1];
  for (int i = beg; i < end; ++i) { row_start[i] = off; off += counts[i]; }
  if (end == n) row_start[n] = off;  // all such threads write the total
}

__global__ void fill_kernel(const int* __restrict__ src, const int* __restrict__ dst,
                            const int* __restrict__ row_start, int* __restrict__ cursor,
                            unsigned short* __restrict__ csr, int E) {
  int e = blockIdx.x * blockDim.x + threadIdx.x;
  if (e < E) {
    int d = dst[e];
    int pos = atomicAdd(&cursor[d], 1);
    csr[row_start[d] + pos] = (unsigned short)src[e];  // N < 65536
  }
}

__global__ void dinv_kernel(const int* __restrict__ degi, float* __restrict__ dinv, int N) {
  int n = blockIdx.x * blockDim.x + threadIdx.x;
  if (n < N) dinv[n] = rsqrtf((float)(degi[n] + 1));  // +1: self-loop
}

// Register-tiled linear on one b-slice:
//   ms[b][r][h] = dinv[r] * sum_f H[b][r][f] * W[h][f]
// Grid = ceil(N/64)*BS; b = blockIdx % BS (XCD-aligned); 256 threads;
// 64 rows x 64 h per block; 4x4 tile per thread in named float4 registers.
__global__ __launch_bounds__(256, 1)  // release VGPR budget; no 64-reg tier spills
void linear_kernel(const float* __restrict__ hin, const float* __restrict__ W,
                   const float* __restrict__ dinv, float* __restrict__ ms,
                   int N, int BS) {
  __shared__ __align__(16) float Xs[64][68];
  __shared__ __align__(16) float Wt[64][68];  // Wt[f][h]
  int t = threadIdx.x;
  int b = blockIdx.x % BS;
  int chunk = blockIdx.x / BS;
  int row0 = chunk * 64;                 // node index within slice
  int nrows = min(64, N - row0);
  size_t sbase = ((size_t)b * N + row0) * 64;

  // stage W transposed (coalesced read, scattered LDS write; once per block)
  for (int i = t; i < 4096; i += 256) {
    int h = i >> 6, f = i & 63;
    Wt[f][h] = W[i];
  }
  // stage X tile: 4 threads per row, each covers 4 float4s (stride 4)
  {
    int rr = t >> 2;   // 0..63
    int c0 = t & 3;
    bool valid = rr < nrows;
    const float* srcp = hin + sbase + (size_t)rr * 64;
#pragma unroll
    for (int c = 0; c < 4; ++c) {
      int f4 = c0 + c * 4;
      float4 v = valid ? reinterpret_cast<const float4*>(srcp)[f4]
                       : float4{0.f, 0.f, 0.f, 0.f};
      *reinterpret_cast<float4*>(&Xs[rr][4 * f4]) = v;
    }
  }
  __syncthreads();

  int hg = t & 15;   // h0 = 4*hg
  int rg = t >> 4;   // r0 = 4*rg
  int r0 = 4 * rg;

  float4 acc0 = {0.f, 0.f, 0.f, 0.f};
  float4 acc1 = {0.f, 0.f, 0.f, 0.f};
  float4 acc2 = {0.f, 0.f, 0.f, 0.f};
  float4 acc3 = {0.f, 0.f, 0.f, 0.f};

// NOTE: macro params must NOT be named x/y/z/w (round-3 compile failure).
#define FMA4(A, S, V)            \
  A.x = fmaf((S), (V).x, A.x);   \
  A.y = fmaf((S), (V).y, A.y);   \
  A.z = fmaf((S), (V).z, A.z);   \
  A.w = fmaf((S), (V).w, A.w);

#pragma unroll
  for (int i = 0; i < 16; ++i) {  // f0 = 4*i
    float4 xr0 = *reinterpret_cast<const float4*>(&Xs[r0 + 0][4 * i]);
    float4 xr1 = *reinterpret_cast<const float4*>(&Xs[r0 + 1][4 * i]);
    float4 xr2 = *reinterpret_cast<const float4*>(&Xs[r0 + 2][4 * i]);
    float4 xr3 = *reinterpret_cast<const float4*>(&Xs[r0 + 3][4 * i]);
    float4 wv0 = *reinterpret_cast<const float4*>(&Wt[4 * i + 0][4 * hg]);
    float4 wv1 = *reinterpret_cast<const float4*>(&Wt[4 * i + 1][4 * hg]);
    float4 wv2 = *reinterpret_cast<const float4*>(&Wt[4 * i + 2][4 * hg]);
    float4 wv3 = *reinterpret_cast<const float4*>(&Wt[4 * i + 3][4 * hg]);
    FMA4(acc0, xr0.x, wv0); FMA4(acc0, xr0.y, wv1); FMA4(acc0, xr0.z, wv2); FMA4(acc0, xr0.w, wv3);
    FMA4(acc1, xr1.x, wv0); FMA4(acc1, xr1.y, wv1); FMA4(acc1, xr1.z, wv2); FMA4(acc1, xr1.w, wv3);
    FMA4(acc2, xr2.x, wv0); FMA4(acc2, xr2.y, wv1); FMA4(acc2, xr2.z, wv2); FMA4(acc2, xr2.w, wv3);
    FMA4(acc3, xr3.x, wv0); FMA4(acc3, xr3.y, wv1); FMA4(acc3, xr3.z, wv2); FMA4(acc3, xr3.w, wv3);
  }
#undef FMA4

  // epilogue: scale by dinv[row] (pre-scaled gather operand), float4 store
#define STORE_S(A, RIDX)                                                   \
  if ((RIDX) < nrows) {                                                    \
    float d = dinv[row0 + (RIDX)];                                         \
    float4 o = {A.x * d, A.y * d, A.z * d, A.w * d};                       \
    reinterpret_cast<float4*>(&ms[sbase + (size_t)(RIDX) * 64])[hg] = o;   \
  }
  STORE_S(acc0, r0 + 0)
  STORE_S(acc1, r0 + 1)
  STORE_S(acc2, r0 + 2)
  STORE_S(acc3, r0 + 3)
#undef STORE_S
}

// Pull aggregation on one b-slice. Grid = ceil(N/8)*BS; b = blockIdx % BS.
// Block = 512 threads = 8 waves; wave = one node. Lane remap: eg = lane>>4
// (edge slot 0..3), hq = lane&15 (h quad). One wave instruction gathers
// 4 edges x 256B from the L2-resident dinv-prescaled ms slice; u16 csr
// indices (L2-cached, NOT nt) prefetched one step ahead. fp32 accum.
template <bool WRITE_H>
__global__ void agg_kernel(const float* __restrict__ ms, const float* __restrict__ dinv,
                           const float* __restrict__ bias, const int* __restrict__ row_start,
                           const unsigned short* __restrict__ csr, float* __restrict__ hout,
                           float* __restrict__ q, const float* __restrict__ fcw,
                           int layer, int L, int N, int BS) {
  int b = blockIdx.x % BS;
  int chunk = blockIdx.x / BS;
  int w = threadIdx.x >> 6, lane = threadIdx.x & 63;
  int n = chunk * 8 + w;
  if (n >= N) return;
  int eg = lane >> 4;     // edge slot 0..3
  int hq = lane & 15;     // h quad: h = 4*hq .. 4*hq+3
  size_t bN = (size_t)b * N;
  const float* mb = ms + bN * 64;

  // self-loop (counted once — eg 0 only)
  f4v acc = {0.f, 0.f, 0.f, 0.f};
  if (eg == 0) {
    acc = *reinterpret_cast<const f4v*>(mb + (size_t)n * 64 + 4 * hq);
  }

  int beg = row_start[n], end = row_start[n + 1];
  int deg = end - beg;
  int i = beg;
  int main_end = beg + (deg & ~3);
  if (i < main_end) {
    int s_cur = csr[i + eg];
    while (true) {
      int inx = i + 4;
      // prefetch next step's index; tail reads the zeroed csr pad (safe, unused)
      int s_next = csr[inx + eg];
      f4v v = *reinterpret_cast<const f4v*>(mb + (size_t)s_cur * 64 + 4 * hq);
      acc += v;
      i = inx;
      if (i >= main_end) break;
      s_cur = s_next;
    }
  }
  int rem = end - i;  // 0..3
  if (rem > 0) {
    int e = i + ((eg < rem) ? eg : 0);
    int s = csr[e];
    f4v v = *reinterpret_cast<const f4v*>(mb + (size_t)s * 64 + 4 * hq);
    if (eg < rem) acc += v;
  }

  // reduce across the 4 edge-slot groups (lanes differing in bits 4,5)
  acc.x += __shfl_xor(acc.x, 16); acc.y += __shfl_xor(acc.y, 16);
  acc.z += __shfl_xor(acc.z, 16); acc.w += __shfl_xor(acc.w, 16);
  acc.x += __shfl_xor(acc.x, 32); acc.y += __shfl_xor(acc.y, 32);
  acc.z += __shfl_xor(acc.z, 32); acc.w += __shfl_xor(acc.w, 32);

  float dn = dinv[n];
  float4 bias4 = *reinterpret_cast<const float4*>(&bias[4 * hq]);
  f4v val;
  val.x = fmaxf(fmaf(dn, acc.x, bias4.x), 0.f);
  val.y = fmaxf(fmaf(dn, acc.y, bias4.y), 0.f);
  val.z = fmaxf(fmaf(dn, acc.z, bias4.z), 0.f);
  val.w = fmaxf(fmaf(dn, acc.w, bias4.w), 0.f);

  if (WRITE_H && eg == 0) {
    // nt store: evict-first so hout streaming doesn't displace the ms slice
    __builtin_nontemporal_store(val,
        reinterpret_cast<f4v*>(hout + bN * 64 + (size_t)n * 64 + 4 * hq));
  }

  // fc_w projection: q[n,b] (+)= sum_h val[h]*fcw[h*L+layer]
  int h0 = 4 * hq;
  float qp = val.x * fcw[(h0 + 0) * L + layer]
           + val.y * fcw[(h0 + 1) * L + layer]
           + val.z * fcw[(h0 + 2) * L + layer]
           + val.w * fcw[(h0 + 3) * L + layer];
  qp += __shfl_xor(qp, 1); qp += __shfl_xor(qp, 2);
  qp += __shfl_xor(qp, 4); qp += __shfl_xor(qp, 8);
  if (lane == 0) {
    if (layer == 0) q[bN + n] = qp;
    else q[bN + n] += qp;
  }
}

__global__ void pathway_kernel(const int* __restrict__ row, const int* __restrict__ col,
                               const float* __restrict__ q, float* __restrict__ s_sum,
                               float* __restrict__ cntc, int R, int N, int BS) {
  int idx = blockIdx.x * blockDim.x + threadIdx.x;
  if (idx >= R * BS) return;
  int r = idx / BS, b = idx - (idx / BS) * BS;
  int c = col[r], nd = row[r];
  atomicAdd(&s_sum[c * BS + b], q[(size_t)b * N + nd]);
  if (b == 0) atomicAdd(&cntc[c], 1.0f);
}

__global__ void head_kernel(const float* __restrict__ s_sum, const float* __restrict__ cntc,
                            const float* __restrict__ fcb, const float* __restrict__ l1w,
                            const float* __restrict__ l1b, const float* __restrict__ l2w,
                            const float* __restrict__ l2b, float* __restrict__ out,
                            int NCMT, int HFC, int NCLS, int BS) {
  int b = blockIdx.x;
  __shared__ float sbuf[400];
  __shared__ float z1[200];
  __shared__ float z2[8];
  int t = threadIdx.x;  // 256
  for (int c = t; c < NCMT; c += 256) {
    float cn = fmaxf(cntc[c], 1.0f);
    sbuf[c] = s_sum[c * BS + b] / cn + fcb[0];
  }
  __syncthreads();
  for (int j = t; j < HFC; j += 256) {
    float a = l1b[j];
    for (int c = 0; c < NCMT; ++c) a = fmaf(sbuf[c], l1w[j * NCMT + c], a);
    z1[j] = fmaxf(a, 0.f);
  }
  __syncthreads();
  if (t < NCLS) {
    float a = l2b[t];
    for (int j = 0; j < HFC; ++j) a = fmaf(z1[j], l2w[t * HFC + j], a);
    z2[t] = a;
  }
  __syncthreads();
  if (t == 0) {
    float mx = z2[0];
    for (int k = 1; k < NCLS; ++k) mx = fmaxf(mx, z2[k]);
    float se = 0.f;
    for (int k = 0; k < NCLS; ++k) se += expf(z2[k] - mx);
    float lse = mx + logf(se);
    for (int k = 0; k < NCLS; ++k) out[b * NCLS + k] = z2[k] - lse;
  }
}

extern "C" void kernel_launch(void* const* d_in, const int* in_sizes, int n_in,
                              void* d_out, int out_size, void* d_ws, size_t ws_size,
                              hipStream_t stream) {
  const float* x   = (const float*)d_in[0];
  const int*  ei   = (const int*)d_in[2];
  const int*  row  = (const int*)d_in[3];
  const int*  col  = (const int*)d_in[4];
  const float* W1  = (const float*)d_in[5];
  const float* b1  = (const float*)d_in[6];
  const float* W2  = (const float*)d_in[7];
  const float* b2  = (const float*)d_in[8];
  const float* W3  = (const float*)d_in[9];
  const float* b3  = (const float*)d_in[10];
  const float* fcw = (const float*)d_in[11];
  const float* fcb = (const float*)d_in[12];
  const float* l1w = (const float*)d_in[13];
  const float* l1b = (const float*)d_in[14];
  const float* l2w = (const float*)d_in[15];
  const float* l2b = (const float*)d_in[16];

  const int BS   = in_sizes[1];               // 8
  const int H    = in_sizes[6];               // 64
  const int F    = in_sizes[5] / H;           // 64
  const int N    = in_sizes[0] / (BS * F);    // 15135
  const int E    = in_sizes[2] / 2;           // 300000
  const int R    = in_sizes[3];               // 40000
  const int HFC  = in_sizes[14];              // 200
  const int NCMT = in_sizes[13] / HFC;        // 400
  const int NCLS = in_sizes[16];              // 2
  const int L    = in_sizes[11] / H;          // 3

  // workspace carve-out (256B aligned)
  char* p = (char*)d_ws;
  auto alloc = [&](size_t bytes) {
    void* r = (void*)p;
    p += (bytes + 255) & ~(size_t)255;
    return r;
  };
  int*   degi      = (int*)alloc((size_t)N * 4);
  int*   cursor    = (int*)alloc((size_t)N * 4);
  int*   row_start = (int*)alloc((size_t)(N + 1) * 4);
  unsigned short* csr = (unsigned short*)alloc((size_t)(E + 8) * 2);  // u16 + prefetch pad
  float* dinv      = (float*)alloc((size_t)N * 4);
  float* q         = (float*)alloc((size_t)N * BS * 4);
  float* s_sum     = (float*)alloc((size_t)NCMT * BS * 4);
  float* cntc      = (float*)alloc((size_t)NCMT * 4);
  float* m         = (float*)alloc((size_t)N * BS * H * 4);
  float* hA        = (float*)alloc((size_t)N * BS * H * 4);
  float* hB        = (float*)alloc((size_t)N * BS * H * 4);

  (void)hipMemsetAsync(degi, 0, (size_t)N * 4, stream);
  (void)hipMemsetAsync(cursor, 0, (size_t)N * 4, stream);
  (void)hipMemsetAsync(csr + E, 0, 16, stream);  // zero the prefetch pad
  (void)hipMemsetAsync(s_sum, 0, (size_t)NCMT * BS * 4, stream);
  (void)hipMemsetAsync(cntc, 0, (size_t)NCMT * 4, stream);

  const int* e_src = ei;
  const int* e_dst = ei + E;

  count_kernel<<<(E + 255) / 256, 256, 0, stream>>>(e_dst, degi, E);
  prefix_kernel<<<1, 1024, 0, stream>>>(degi, row_start, N);
  fill_kernel<<<(E + 255) / 256, 256, 0, stream>>>(e_src, e_dst, row_start, cursor, csr, E);
  dinv_kernel<<<(N + 255) / 256, 256, 0, stream>>>(degi, dinv, N);

  int lin_grid = ((N + 63) / 64) * BS;   // b = blockIdx % BS -> XCD-pinned slices
  int agg_grid = ((N + 7) / 8) * BS;
  int agg_threads = 512;                 // 8 waves = 8 nodes per block

  // layer 1 (x is fp32 [b][n][f])
  linear_kernel<<<lin_grid, 256, 0, stream>>>(x, W1, dinv, m, N, BS);
  agg_kernel<true><<<agg_grid, agg_threads, 0, stream>>>(m, dinv, b1, row_start, csr, hA, q, fcw, 0, L, N, BS);
  // layer 2
  linear_kernel<<<lin_grid, 256, 0, stream>>>(hA, W2, dinv, m, N, BS);
  agg_kernel<true><<<agg_grid, agg_threads, 0, stream>>>(m, dinv, b2, row_start, csr, hB, q, fcw, 1, L, N, BS);
  // layer 3 — hout is dead (only q survives), skip the store
  linear_kernel<<<lin_grid, 256, 0, stream>>>(hB, W3, dinv, m, N, BS);
  agg_kernel<false><<<agg_grid, agg_threads, 0, stream>>>(m, dinv, b3, row_start, csr, nullptr, q, fcw, 2, L, N, BS);

  pathway_kernel<<<((size_t)R * BS + 255) / 256, 256, 0, stream>>>(row, col, q, s_sum, cntc, R, N, BS);
  head_kernel<<<BS, 256, 0, stream>>>(s_sum, cntc, fcb, l1w, l1b, l2w, l2b,
                                      (float*)d_out, NCMT, HFC, NCLS, BS);
}